// Round 2
// baseline (945.718 us; speedup 1.0000x reference)
//
#include <hip/hip_runtime.h>
#include <hip/hip_bf16.h>
#include <hip/hip_cooperative_groups.h>

namespace cg = cooperative_groups;

// GCN encoder: out = concat(h1, h2), h_l = relu(Dinv(A+I)Dinv (x@W_l) + b_l)
// Inputs: x[N,128], W1,W2[128,128], b1,b2[128] = float32; edge_index int32 [2,E]
// Output: float32 [N,256] (harness compares vs bf16-emulated np ref, 2% rel).
//
// Round 7: ONE cooperative mega-kernel. Round-1 evidence: agg improved 3.7us
// but total got 5.4us WORSE -> ~247us of the 387 is outside the two visible
// agg dispatches, and no other kernel ever surfaces in top-5 (<70us each),
// while bottom-up kernel estimates sum to ~100us. Theory: per-dispatch launch
// overhead across the 9-deep serialized pipeline. Fix: fuse everything into
// mega_k with grid.sync() between the 7 phases (zero+transpose / bin / build /
// gemm1 / agg1 / gemm2 / agg2). Co-residency: __launch_bounds__(256,4),
// LDS union 26.4KB (bin CAPL 64->32; build re-reads gBuf instead of staging
// 49KB in LDS). Legacy multi-launch path kept as fallback if the cooperative
// launch is refused. Phase bodies are the round-1-verified kernels, shared
// between both paths as inline device functions.
//
// ws layout (bytes):
#define OFF_GCNT 0x0000000   // int[196]     bucket cursors
#define OFF_RP   0x0001000   // int[N+1]     CSR row pointers
#define OFF_DINV 0x0070000   // float[N]     rsqrt(deg+1)
#define OFF_WT1  0x00E0000   // bf16[128*128] W1^T
#define OFF_WT2  0x00E8000   // bf16[128*128] W2^T
#define OFF_COL  0x00F0000   // int[E]       CSR col (src) ids
#define OFF_G    0x0710000   // overlay: gBuf (9.6MB, dead after build) then
                             //          bf16 G[N*128] (25.6MB)
#define OFF_H1   0x1F80000   // bf16[N*128]  h1 staged for layer-2 GEMM
#define WS_NEED  0x3800000   // ~58.7MB if H1 used; 33MB min otherwise

#define CAPL   32      // LDS slots per bucket in bin (32 -> union fits 4 blk/CU)
#define MAXNBK 200     // static LDS sizing (actual NBK=196 for N=100000)
#define CAP2   12288   // global slots per bucket (avg fill 8163, +45 sigma)

typedef short bf16x8 __attribute__((ext_vector_type(8)));
typedef float f32x4 __attribute__((ext_vector_type(4)));
typedef float f32x2 __attribute__((ext_vector_type(2)));
typedef unsigned int u32x4 __attribute__((ext_vector_type(4)));

static __device__ __forceinline__ unsigned short f2bf(float f) {
    unsigned int u = __float_as_uint(f);
    u = u + 0x7fffu + ((u >> 16) & 1u);   // round-to-nearest-even
    return (unsigned short)(u >> 16);
}

// ---------- shared LDS union (max 26.4KB -> 4+ blocks/CU) ----------
struct SmBin { int lcnt[MAXNBK]; unsigned lbuf[MAXNBK * CAPL]; };
struct SmBld { int bc[256]; int tmp[256]; int ncnt[512]; int nrp[512]; int ncur[512]; };
union SmU { SmBin bin; SmBld bld; };

// ---------- phase bodies (shared by mega_k and legacy kernels) ----------

// bin: bucket 4096 edges of chunk c into 196 dst-buckets via LDS, bulk-flush.
static __device__ __forceinline__ void bin_block(
    int c, const int* __restrict__ src, const int* __restrict__ dst,
    int* __restrict__ gCnt, unsigned* __restrict__ gBuf, int E, int NBK,
    SmBin& sm) {
    int t = threadIdx.x;
    for (int i = t; i < NBK; i += 256) sm.lcnt[i] = 0;
    __syncthreads();
    int base = c * 4096;
#pragma unroll 4
    for (int j = 0; j < 16; j++) {
        int e = base + j * 256 + t;
        if (e < E) {
            int d = dst[e], s = src[e];
            int b = d >> 9;
            unsigned entry = ((unsigned)(d & 511) << 23) | (unsigned)s;
            int pos = atomicAdd(&sm.lcnt[b], 1);
            if (pos < CAPL) {
                sm.lbuf[b * CAPL + pos] = entry;
            } else {            // overflow spill (~1% of buckets at CAPL=32)
                int gp = atomicAdd(&gCnt[b], 1);
                if (gp < CAP2) gBuf[(size_t)b * CAP2 + gp] = entry;
            }
        }
    }
    __syncthreads();
    for (int b = t; b < NBK; b += 256) {
        int n = sm.lcnt[b]; if (n > CAPL) n = CAPL;
        if (n) {
            int gp = atomicAdd(&gCnt[b], n);
            for (int k = 0; k < n; k++) {
                int p = gp + k;
                if (p < CAP2) gBuf[(size_t)b * CAP2 + p] = sm.lbuf[b * CAPL + k];
            }
        }
    }
    __syncthreads();   // lcnt/lbuf reused by next chunk iteration
}

// build: counting sort of bucket b -> rp, dinv, col. Reads gBuf twice
// (L2-hot 32KB) instead of staging in 49KB LDS.
static __device__ __forceinline__ void build_block(
    int b, const unsigned* __restrict__ gBuf, const int* __restrict__ gCnt,
    int* __restrict__ rp, float* __restrict__ dinv, int* __restrict__ col,
    int NBK, int N, SmBld& sm) {
    int t = threadIdx.x;

    // scan bucket counts -> colBase
    int c = (t < NBK) ? gCnt[t] : 0;
    if (c > CAP2) c = CAP2;
    sm.bc[t] = c;
    sm.tmp[t] = c;
    __syncthreads();
    for (int off = 1; off < 256; off <<= 1) {
        int x = (t >= off) ? sm.tmp[t - off] : 0;
        __syncthreads(); sm.tmp[t] += x; __syncthreads();
    }
    int colBase = sm.tmp[b] - sm.bc[b];
    int total = sm.tmp[255];
    int cntb = sm.bc[b];
    if (b == 0 && t == 0) rp[N] = total;

    sm.ncnt[t] = 0; sm.ncnt[t + 256] = 0;
    __syncthreads();

    const unsigned* gbp = gBuf + (size_t)b * CAP2;
    // pass A: per-node counts
    for (int k = t; k < cntb; k += 256) atomicAdd(&sm.ncnt[gbp[k] >> 23], 1);
    __syncthreads();

    // exclusive scan of 512 counts with 256 threads
    int v0 = sm.ncnt[2 * t], v1 = sm.ncnt[2 * t + 1];
    int ps = v0 + v1;
    sm.tmp[t] = ps;
    __syncthreads();
    for (int off = 1; off < 256; off <<= 1) {
        int x = (t >= off) ? sm.tmp[t - off] : 0;
        __syncthreads(); sm.tmp[t] += x; __syncthreads();
    }
    int ex = sm.tmp[t] - ps;
    sm.nrp[2 * t] = ex;          sm.ncur[2 * t] = ex;
    sm.nrp[2 * t + 1] = ex + v0; sm.ncur[2 * t + 1] = ex + v0;
    __syncthreads();

    // rp + dinv (coalesced)
    int g0 = b << 9;
    for (int i = t; i < 512; i += 256) {
        int g = g0 + i;
        if (g < N) {
            rp[g] = colBase + sm.nrp[i];
            dinv[g] = rsqrtf((float)(sm.ncnt[i] + 1));
        }
    }
    __syncthreads();

    // pass B: place into col (scatter confined to this bucket's region)
    for (int k = t; k < cntb; k += 256) {
        unsigned e = gbp[k];
        int dl = e >> 23;
        int s = (int)(e & 0x7fffffu);
        int pos = atomicAdd(&sm.ncur[dl], 1);
        col[colBase + pos] = s;
    }
    __syncthreads();   // sm reused by next bucket iteration
}

// gemm: G[r,:] = bf16( (A[r,:] @ W) * dinv[r] ) for the 64-row tile tb.
template <int AF32>
static __device__ __forceinline__ void gemm_block(
    const void* __restrict__ Av, int lda,
    const unsigned short* __restrict__ WT,
    const float* __restrict__ dinv,
    unsigned short* __restrict__ G, int M, int tb) {
    int wave = threadIdx.x >> 6;
    int lane = threadIdx.x & 63;
    int quad = lane >> 4;
    int l16  = lane & 15;
    int rowBase = tb * 64 + wave * 16;
    int rowc = rowBase + l16;
    if (rowc > M - 1) rowc = M - 1;

    f32x4 acc[8];
#pragma unroll
    for (int t = 0; t < 8; t++) acc[t] = (f32x4){0.f, 0.f, 0.f, 0.f};

#pragma unroll
    for (int kk = 0; kk < 128; kk += 32) {
        bf16x8 a;
        if (AF32) {
            const float* Af = (const float*)Av;
            const f32x4* ap = (const f32x4*)(Af + (size_t)rowc * lda + kk + quad * 8);
            f32x4 a0 = __builtin_nontemporal_load(ap);
            f32x4 a1 = __builtin_nontemporal_load(ap + 1);
#pragma unroll
            for (int j = 0; j < 4; j++) {
                a[j]     = (short)f2bf(a0[j]);
                a[j + 4] = (short)f2bf(a1[j]);
            }
        } else {
            const unsigned short* Ab = (const unsigned short*)Av;
            a = __builtin_nontemporal_load(
                    (const bf16x8*)(Ab + (size_t)rowc * lda + kk + quad * 8));
        }
#pragma unroll
        for (int t = 0; t < 8; t++) {
            bf16x8 b = *(const bf16x8*)(WT + (t * 16 + l16) * 128 + kk + quad * 8);
            acc[t] = __builtin_amdgcn_mfma_f32_16x16x32_bf16(a, b, acc[t], 0, 0, 0);
        }
    }
    // D layout: row = quad*4 + reg, col = l16 (within each 16x16 tile t)
#pragma unroll
    for (int r = 0; r < 4; r++) {
        int orow = rowBase + quad * 4 + r;
        if (orow < M) {
            float di = dinv[orow];
#pragma unroll
            for (int t = 0; t < 8; t++) {
                G[(size_t)orow * 128 + t * 16 + l16] = f2bf(acc[t][r] * di);
            }
        }
    }
}

// agg: out[n,:] = relu(dinv[n]*(g[n,:] + sum_{s in N(n)} g[s,:]) + b) for the
// 4 nodes of block-iteration blk (one wave per node; 4 slots in flight per
// 16-lane group; see round-6 notes).
static __device__ __forceinline__ void accum8(f32x2* acc, u32x4 v) {
#pragma unroll
    for (int d = 0; d < 4; d++) {
        f32x2 t;
        t[0] = __uint_as_float(v[d] << 16);
        t[1] = __uint_as_float(v[d] & 0xffff0000u);
        acc[d] += t;                       // v_pk_add_f32
    }
}

static __device__ __forceinline__ void agg_block(
    const unsigned short* __restrict__ G,
    const int* __restrict__ rp, const int* __restrict__ col,
    const float* __restrict__ dinv, const float* __restrict__ bias,
    float* __restrict__ Out, unsigned short* __restrict__ H,
    int colbase, int N, int blk) {
    int gid = blk * 4 + (threadIdx.x >> 6);
    if (gid >= N) return;   // wave-uniform; only used inside non-sync regions
    int lane = threadIdx.x & 63;
    int g = lane >> 4, i = lane & 15;

    f32x2 acc[4];
#pragma unroll
    for (int j = 0; j < 4; j++) acc[j] = (f32x2){0.f, 0.f};

    int e0 = rp[gid], e1 = rp[gid + 1];
    // virtual slot list: index e0-1 == self, then col[e0..e1).
    // group g owns slots e0-1+g, +4, +8, ... ; window of 4 in flight.
    int my = e0 - 1 + g;
    int c0 = (my < e1) ? ((my >= e0) ? __builtin_nontemporal_load(col + my) : gid)
                       : -1; my += 4;
    int c1 = (my < e1) ? __builtin_nontemporal_load(col + my) : -1; my += 4;
    int c2 = (my < e1) ? __builtin_nontemporal_load(col + my) : -1; my += 4;
    int c3 = (my < e1) ? __builtin_nontemporal_load(col + my) : -1; my += 4;

    const unsigned short* Gi = G + (size_t)i * 8;

    while (c0 >= 0) {
        int n0 = (my < e1) ? __builtin_nontemporal_load(col + my) : -1; my += 4;
        int n1 = (my < e1) ? __builtin_nontemporal_load(col + my) : -1; my += 4;
        int n2 = (my < e1) ? __builtin_nontemporal_load(col + my) : -1; my += 4;
        int n3 = (my < e1) ? __builtin_nontemporal_load(col + my) : -1; my += 4;
        int a1 = (c1 >= 0) ? c1 : gid;
        int a2 = (c2 >= 0) ? c2 : gid;
        int a3 = (c3 >= 0) ? c3 : gid;
        u32x4 v0 = *(const u32x4*)(Gi + (size_t)c0 * 128);
        u32x4 v1 = *(const u32x4*)(Gi + (size_t)a1 * 128);
        u32x4 v2 = *(const u32x4*)(Gi + (size_t)a2 * 128);
        u32x4 v3 = *(const u32x4*)(Gi + (size_t)a3 * 128);
        accum8(acc, v0);
        if (c1 >= 0) accum8(acc, v1);
        if (c2 >= 0) accum8(acc, v2);
        if (c3 >= 0) accum8(acc, v3);
        c0 = n0; c1 = n1; c2 = n2; c3 = n3;
    }

    float a8[8];
#pragma unroll
    for (int d = 0; d < 4; d++) { a8[2 * d] = acc[d][0]; a8[2 * d + 1] = acc[d][1]; }
#pragma unroll
    for (int j = 0; j < 8; j++) a8[j] += __shfl_xor(a8[j], 16, 64);
#pragma unroll
    for (int j = 0; j < 8; j++) a8[j] += __shfl_xor(a8[j], 32, 64);

    if (g == 0) {
        float di = dinv[gid];
        const f32x4* bp = (const f32x4*)(bias + i * 8);
        f32x4 b0 = bp[0], b1 = bp[1];
        f32x4 o0, o1;
#pragma unroll
        for (int j = 0; j < 4; j++) {
            o0[j] = fmaxf(a8[j] * di + b0[j], 0.f);
            o1[j] = fmaxf(a8[j + 4] * di + b1[j], 0.f);
        }
        float* orow = Out + (size_t)gid * 256 + colbase + i * 8;
        __builtin_nontemporal_store(o0, (f32x4*)orow);
        __builtin_nontemporal_store(o1, (f32x4*)(orow + 4));
        if (H) {
            bf16x8 hv;
#pragma unroll
            for (int j = 0; j < 4; j++) {
                hv[j]     = (short)f2bf(o0[j]);
                hv[j + 4] = (short)f2bf(o1[j]);
            }
            __builtin_nontemporal_store(hv, (bf16x8*)(H + (size_t)gid * 128 + i * 8));
        }
    }
}

// ---------- the cooperative mega-kernel ----------
__global__ __launch_bounds__(256, 4) void mega_k(
    const float* __restrict__ x, const float* __restrict__ W1,
    const float* __restrict__ b1, const float* __restrict__ W2,
    const float* __restrict__ b2, const int* __restrict__ src,
    const int* __restrict__ dst, int* __restrict__ gCnt,
    int* __restrict__ rp, float* __restrict__ dinv,
    unsigned short* __restrict__ WT1, unsigned short* __restrict__ WT2,
    int* __restrict__ col, unsigned* __restrict__ gBuf,
    unsigned short* __restrict__ G, unsigned short* __restrict__ H1,
    float* __restrict__ out, int E, int N, int NBK) {
    cg::grid_group grid = cg::this_grid();
    __shared__ SmU sm;
    const int t = threadIdx.x;
    const int nb = gridDim.x;
    const int gstep = nb * 256;

    // phase 0: zero gCnt + transpose/cvt W1,W2
    for (int i = blockIdx.x * 256 + t; i < NBK; i += gstep) gCnt[i] = 0;
    for (int i = blockIdx.x * 256 + t; i < 16384; i += gstep) {
        int n = i >> 7, k = i & 127;
        WT1[i] = f2bf(W1[k * 128 + n]);
        WT2[i] = f2bf(W2[k * 128 + n]);
    }
    grid.sync();

    // phase 1: bin edges into buckets
    int chunks = (E + 4095) >> 12;
    for (int c = blockIdx.x; c < chunks; c += nb)
        bin_block(c, src, dst, gCnt, gBuf, E, NBK, sm.bin);
    grid.sync();

    // phase 2: per-bucket counting sort -> rp, dinv, col
    for (int b = blockIdx.x; b < NBK; b += nb)
        build_block(b, gBuf, gCnt, rp, dinv, col, NBK, N, sm.bld);
    grid.sync();

    // phase 3: gemm layer 1 (A = x, f32); G overlays gBuf (dead now)
    int gb_ = (N + 63) >> 6;
    for (int tb = blockIdx.x; tb < gb_; tb += nb)
        gemm_block<1>(x, 128, WT1, dinv, G, N, tb);
    grid.sync();

    // phase 4: aggregate layer 1 -> out[:,0:128], stage H1
    int ab_ = (N + 3) >> 2;
    for (int blk = blockIdx.x; blk < ab_; blk += nb)
        agg_block(G, rp, col, dinv, b1, out, H1, 0, N, blk);
    grid.sync();

    // phase 5: gemm layer 2
    if (H1) {
        for (int tb = blockIdx.x; tb < gb_; tb += nb)
            gemm_block<0>(H1, 128, WT2, dinv, G, N, tb);
    } else {
        for (int tb = blockIdx.x; tb < gb_; tb += nb)
            gemm_block<1>(out, 256, WT2, dinv, G, N, tb);
    }
    grid.sync();

    // phase 6: aggregate layer 2 -> out[:,128:256]
    for (int blk = blockIdx.x; blk < ab_; blk += nb)
        agg_block(G, rp, col, dinv, b2, out, nullptr, 128, N, blk);
}

// ---------- legacy fallback kernels (round-1-verified path) ----------
__global__ __launch_bounds__(256) void bin_k(
    const int* __restrict__ src, const int* __restrict__ dst,
    int* __restrict__ gCnt, unsigned* __restrict__ gBuf, int E, int NBK) {
    __shared__ SmBin sm;
    bin_block(blockIdx.x, src, dst, gCnt, gBuf, E, NBK, sm);
}

__global__ __launch_bounds__(256) void build_k(
    const unsigned* __restrict__ gBuf, const int* __restrict__ gCnt,
    int* __restrict__ rp, float* __restrict__ dinv, int* __restrict__ col,
    int NBK, int N) {
    __shared__ SmBld sm;
    build_block(blockIdx.x, gBuf, gCnt, rp, dinv, col, NBK, N, sm);
}

__global__ void transpose_w(const float* __restrict__ W,
                            unsigned short* __restrict__ WT) {
    int idx = blockIdx.x * 256 + threadIdx.x;
    int n = idx >> 7, k = idx & 127;
    WT[idx] = f2bf(W[k * 128 + n]);
}

template <int AF32>
__global__ __launch_bounds__(256) void gemm_scale(
    const void* __restrict__ Av, int lda,
    const unsigned short* __restrict__ WT,
    const float* __restrict__ dinv,
    unsigned short* __restrict__ G, int M) {
    gemm_block<AF32>(Av, lda, WT, dinv, G, M, blockIdx.x);
}

__global__ __launch_bounds__(256) void agg_k(
    const unsigned short* __restrict__ G,
    const int* __restrict__ rp, const int* __restrict__ col,
    const float* __restrict__ dinv, const float* __restrict__ bias,
    float* __restrict__ Out, unsigned short* __restrict__ H,
    int colbase, int N) {
    agg_block(G, rp, col, dinv, bias, Out, H, colbase, N, blockIdx.x);
}

extern "C" void kernel_launch(void* const* d_in, const int* in_sizes, int n_in,
                              void* d_out, int out_size, void* d_ws, size_t ws_size,
                              hipStream_t stream) {
    const float* x  = (const float*)d_in[0];   // [N,128] f32
    const float* W1 = (const float*)d_in[1];   // [128,128] f32
    const float* b1 = (const float*)d_in[2];   // [128] f32
    const float* W2 = (const float*)d_in[3];
    const float* b2 = (const float*)d_in[4];
    const int* ei = (const int*)d_in[5];       // [2,E] int32

    const int N = in_sizes[0] / 128;
    const int E = in_sizes[5] / 2;
    const int* src = ei;
    const int* dst = ei + E;
    const int NBK = (N + 511) >> 9;            // 196 for N=100000 (<= MAXNBK)

    char* ws = (char*)d_ws;
    int*      gCnt = (int*)(ws + OFF_GCNT);
    int*      rp   = (int*)(ws + OFF_RP);
    float*    dinv = (float*)(ws + OFF_DINV);
    unsigned short* WT1 = (unsigned short*)(ws + OFF_WT1);
    unsigned short* WT2 = (unsigned short*)(ws + OFF_WT2);
    int*      col  = (int*)(ws + OFF_COL);
    unsigned* gBuf = (unsigned*)(ws + OFF_G);          // dead after build
    unsigned short* G = (unsigned short*)(ws + OFF_G); // overlays gBuf
    unsigned short* H1 = (ws_size >= (size_t)WS_NEED)
                         ? (unsigned short*)(ws + OFF_H1) : nullptr;
    float* out = (float*)d_out;

    // one-time co-residency sizing for the cooperative launch
    static int coopBlocks = -2;                 // -2 uninit, -1 disabled
    if (coopBlocks == -2) {
        int dev = 0; (void)hipGetDevice(&dev);
        int nCU = 0;
        hipError_t e1 = hipDeviceGetAttribute(
            &nCU, hipDeviceAttributeMultiprocessorCount, dev);
        int bpc = 0;
        hipError_t e2 = hipOccupancyMaxActiveBlocksPerMultiprocessor(
            &bpc, (const void*)mega_k, 256, 0);
        coopBlocks = (e1 == hipSuccess && e2 == hipSuccess && nCU > 0 && bpc > 0)
                     ? nCU * bpc : -1;
    }

    bool done = false;
    if (coopBlocks > 0) {
        void* args[] = { (void*)&x, (void*)&W1, (void*)&b1, (void*)&W2,
                         (void*)&b2, (void*)&src, (void*)&dst, (void*)&gCnt,
                         (void*)&rp, (void*)&dinv, (void*)&WT1, (void*)&WT2,
                         (void*)&col, (void*)&gBuf, (void*)&G, (void*)&H1,
                         (void*)&out, (void*)&E, (void*)&N, (void*)&NBK };
        hipError_t rc = hipLaunchCooperativeKernel(
            (const void*)mega_k, dim3(coopBlocks), dim3(256), args, 0, stream);
        if (rc == hipSuccess) done = true;
        else coopBlocks = -1;                   // don't retry next calls
    }

    if (!done) {   // legacy 9-dispatch path (round-1-verified)
        hipMemsetAsync(gCnt, 0, (size_t)NBK * sizeof(int), stream);
        transpose_w<<<64, 256, 0, stream>>>(W1, WT1);
        transpose_w<<<64, 256, 0, stream>>>(W2, WT2);
        bin_k<<<(E + 4095) / 4096, 256, 0, stream>>>(src, dst, gCnt, gBuf, E, NBK);
        build_k<<<NBK, 256, 0, stream>>>(gBuf, gCnt, rp, dinv, col, NBK, N);
        int gb = (N + 63) / 64;
        int ab = (N + 3) / 4;
        gemm_scale<1><<<gb, 256, 0, stream>>>(x, 128, WT1, dinv, G, N);
        agg_k<<<ab, 256, 0, stream>>>(G, rp, col, dinv, b1, out, H1, 0, N);
        if (H1) {
            gemm_scale<0><<<gb, 256, 0, stream>>>(H1, 128, WT2, dinv, G, N);
        } else {
            gemm_scale<1><<<gb, 256, 0, stream>>>(out, 256, WT2, dinv, G, N);
        }
        agg_k<<<ab, 256, 0, stream>>>(G, rp, col, dinv, b2, out, nullptr, 128, N);
    }
}

// Round 3
// 384.156 us; speedup vs baseline: 2.4618x; 2.4618x over previous
//
#include <hip/hip_runtime.h>
#include <hip/hip_bf16.h>

// GCN encoder: out = concat(h1, h2), h_l = relu(Dinv(A+I)Dinv (x@W_l) + b_l)
// Inputs: x[N,128], W1,W2[128,128], b1,b2[128] = float32; edge_index int32 [2,E]
// Output: float32 [N,256] (harness compares vs bf16-emulated np ref, 2% rel).
//
// Round 8: revert the cooperative mega-kernel (round 7: 1110us kernel-internal,
// 4.7x the legacy kernel-sum -- grid.sync's device-scope fences flush per-XCD
// L2 between phases, killing all cross-phase locality; occupancy capped at 4
// blk/CU hurt every phase). Back to the round-6 multi-launch pipeline, with
// ONE change: dispatch count 9 -> 7. memset(gCnt) + transpose(W1) +
// transpose(W2) fold into a single prep_k. All hot kernels (bin/build/gemm/
// agg) are byte-identical to round 6. This is a controlled test of the
// per-dispatch-overhead hypothesis: total should drop ~2x the per-dispatch
// overhead while every kernel's own counters stay identical.
//
// ws layout (bytes):
#define OFF_GCNT 0x0000000   // int[196]     bucket cursors (zeroed by prep_k)
#define OFF_RP   0x0001000   // int[N+1]     CSR row pointers
#define OFF_DINV 0x0070000   // float[N]     rsqrt(deg+1)
#define OFF_WT1  0x00E0000   // bf16[128*128] W1^T
#define OFF_WT2  0x00E8000   // bf16[128*128] W2^T
#define OFF_COL  0x00F0000   // int[E]       CSR col (src) ids
#define OFF_G    0x0710000   // overlay: gBuf (9.6MB, dead after build_k) then
                             //          bf16 G[N*128] (25.6MB)
#define OFF_H1   0x1F80000   // bf16[N*128]  h1 staged for layer-2 GEMM
#define WS_NEED  0x3800000   // ~58.7MB if H1 used; 33MB min otherwise

#define CAPL   64      // LDS slots per bucket in bin_k
#define MAXNBK 200     // static LDS sizing (actual NBK=196 for N=100000)
#define CAP2   12288   // global slots per bucket (avg fill 8163, +45 sigma)

typedef short bf16x8 __attribute__((ext_vector_type(8)));
typedef float f32x4 __attribute__((ext_vector_type(4)));
typedef float f32x2 __attribute__((ext_vector_type(2)));
typedef unsigned int u32x4 __attribute__((ext_vector_type(4)));

static __device__ __forceinline__ unsigned short f2bf(float f) {
    unsigned int u = __float_as_uint(f);
    u = u + 0x7fffu + ((u >> 16) & 1u);   // round-to-nearest-even
    return (unsigned short)(u >> 16);
}

// ---------- phase 0: zero gCnt + transpose/cvt W1,W2 (one dispatch) ----------
__global__ __launch_bounds__(256) void prep_k(
    const float* __restrict__ W1, const float* __restrict__ W2,
    unsigned short* __restrict__ WT1, unsigned short* __restrict__ WT2,
    int* __restrict__ gCnt, int NBK) {
    int idx = blockIdx.x * 256 + threadIdx.x;   // grid 64 -> 16384
    int n = idx >> 7, k = idx & 127;
    WT1[idx] = f2bf(W1[k * 128 + n]);
    WT2[idx] = f2bf(W2[k * 128 + n]);
    if (blockIdx.x == 0 && threadIdx.x < NBK) gCnt[threadIdx.x] = 0;
}

// ---------- phase 1: LDS-binned edge bucketing ----------
__global__ __launch_bounds__(256) void bin_k(
    const int* __restrict__ src, const int* __restrict__ dst,
    int* __restrict__ gCnt, unsigned* __restrict__ gBuf, int E, int NBK) {
    __shared__ int lcnt[MAXNBK];
    __shared__ unsigned lbuf[MAXNBK * CAPL];
    for (int i = threadIdx.x; i < NBK; i += 256) lcnt[i] = 0;
    __syncthreads();
    int base = blockIdx.x * 4096;
#pragma unroll 4
    for (int j = 0; j < 16; j++) {
        int e = base + j * 256 + threadIdx.x;
        if (e < E) {
            int d = dst[e], s = src[e];
            int b = d >> 9;
            unsigned entry = ((unsigned)(d & 511) << 23) | (unsigned)s;
            int pos = atomicAdd(&lcnt[b], 1);
            if (pos < CAPL) {
                lbuf[b * CAPL + pos] = entry;
            } else {            // overflow spill (statistically never at CAPL=64)
                int gp = atomicAdd(&gCnt[b], 1);
                if (gp < CAP2) gBuf[(size_t)b * CAP2 + gp] = entry;
            }
        }
    }
    __syncthreads();
    for (int b = threadIdx.x; b < NBK; b += 256) {
        int n = lcnt[b]; if (n > CAPL) n = CAPL;
        if (n) {
            int gp = atomicAdd(&gCnt[b], n);
            for (int k = 0; k < n; k++) {
                int p = gp + k;
                if (p < CAP2) gBuf[(size_t)b * CAP2 + p] = lbuf[b * CAPL + k];
            }
        }
    }
}

// ---------- phase 2: per-bucket counting sort -> rp, dinv, col ----------
__global__ __launch_bounds__(256) void build_k(
    const unsigned* __restrict__ gBuf, const int* __restrict__ gCnt,
    int* __restrict__ rp, float* __restrict__ dinv, int* __restrict__ col,
    int NBK, int N) {
    __shared__ unsigned entries[CAP2];
    __shared__ int bc[256], tmp[256];
    __shared__ int ncnt[512], nrp[512], ncur[512];
    int t = threadIdx.x, b = blockIdx.x;

    // scan bucket counts -> colBase
    int c = (t < NBK) ? gCnt[t] : 0;
    if (c > CAP2) c = CAP2;
    bc[t] = c;
    tmp[t] = c;
    __syncthreads();
    for (int off = 1; off < 256; off <<= 1) {
        int x = (t >= off) ? tmp[t - off] : 0;
        __syncthreads(); tmp[t] += x; __syncthreads();
    }
    int colBase = tmp[b] - bc[b];
    int total = tmp[255];
    int cntb = bc[b];
    if (b == 0 && t == 0) rp[N] = total;

    // load this bucket's entries
    for (int k = t; k < cntb; k += 256) entries[k] = gBuf[(size_t)b * CAP2 + k];
    ncnt[t] = 0; ncnt[t + 256] = 0;
    __syncthreads();

    // pass A: per-node counts
    for (int k = t; k < cntb; k += 256) atomicAdd(&ncnt[entries[k] >> 23], 1);
    __syncthreads();

    // exclusive scan of 512 counts with 256 threads
    int v0 = ncnt[2 * t], v1 = ncnt[2 * t + 1];
    int ps = v0 + v1;
    tmp[t] = ps;
    __syncthreads();
    for (int off = 1; off < 256; off <<= 1) {
        int x = (t >= off) ? tmp[t - off] : 0;
        __syncthreads(); tmp[t] += x; __syncthreads();
    }
    int ex = tmp[t] - ps;
    nrp[2 * t] = ex;          ncur[2 * t] = ex;
    nrp[2 * t + 1] = ex + v0; ncur[2 * t + 1] = ex + v0;
    __syncthreads();

    // rp + dinv (coalesced)
    int g0 = b << 9;
    for (int i = t; i < 512; i += 256) {
        int g = g0 + i;
        if (g < N) {
            rp[g] = colBase + nrp[i];
            dinv[g] = rsqrtf((float)(ncnt[i] + 1));
        }
    }
    __syncthreads();

    // pass B: place into col (scatter confined to this bucket's region)
    for (int k = t; k < cntb; k += 256) {
        unsigned e = entries[k];
        int dl = e >> 23;
        int s = (int)(e & 0x7fffffu);
        int pos = atomicAdd(&ncur[dl], 1);
        col[colBase + pos] = s;
    }
}

// ---------- GEMM: G[r,:] = bf16( (A[r,:] @ W) * dinv[r] ) ----------
// AF32=1: A is float32 [M,lda]; AF32=0: A is bf16 (ushort) [M,lda]
template <int AF32>
__global__ __launch_bounds__(256) void gemm_scale(
    const void* __restrict__ Av, int lda,
    const unsigned short* __restrict__ WT,
    const float* __restrict__ dinv,
    unsigned short* __restrict__ G, int M) {
    int wave = threadIdx.x >> 6;
    int lane = threadIdx.x & 63;
    int quad = lane >> 4;
    int l16  = lane & 15;
    int rowBase = blockIdx.x * 64 + wave * 16;
    int rowc = rowBase + l16;
    if (rowc > M - 1) rowc = M - 1;

    f32x4 acc[8];
#pragma unroll
    for (int t = 0; t < 8; t++) acc[t] = (f32x4){0.f, 0.f, 0.f, 0.f};

#pragma unroll
    for (int kk = 0; kk < 128; kk += 32) {
        bf16x8 a;
        if (AF32) {
            const float* Af = (const float*)Av;
            const f32x4* ap = (const f32x4*)(Af + (size_t)rowc * lda + kk + quad * 8);
            f32x4 a0 = __builtin_nontemporal_load(ap);
            f32x4 a1 = __builtin_nontemporal_load(ap + 1);
#pragma unroll
            for (int j = 0; j < 4; j++) {
                a[j]     = (short)f2bf(a0[j]);
                a[j + 4] = (short)f2bf(a1[j]);
            }
        } else {
            const unsigned short* Ab = (const unsigned short*)Av;
            a = __builtin_nontemporal_load(
                    (const bf16x8*)(Ab + (size_t)rowc * lda + kk + quad * 8));
        }
#pragma unroll
        for (int t = 0; t < 8; t++) {
            bf16x8 b = *(const bf16x8*)(WT + (t * 16 + l16) * 128 + kk + quad * 8);
            acc[t] = __builtin_amdgcn_mfma_f32_16x16x32_bf16(a, b, acc[t], 0, 0, 0);
        }
    }
    // D layout: row = quad*4 + reg, col = l16 (within each 16x16 tile t)
#pragma unroll
    for (int r = 0; r < 4; r++) {
        int orow = rowBase + quad * 4 + r;
        if (orow < M) {
            float di = dinv[orow];
#pragma unroll
            for (int t = 0; t < 8; t++) {
                G[(size_t)orow * 128 + t * 16 + l16] = f2bf(acc[t][r] * di);
            }
        }
    }
}

// ---------- Aggregate ----------
// out[n,:] = relu(dinv[n]*(g[n,:] + sum_{s in N(n)} g[s,:]) + b)
// One wave per node. lane = 16*g + i: group g processes edge slots g, g+4,
// g+8,... (slot e0-1 = self-loop); lane loads channels [8i, 8i+8) as 16B.
// Four slots in flight per group; invalid slots clamp to the self row and
// their accumulate is predicated off. NT stores for Out/H.
static __device__ __forceinline__ void accum8(f32x2* acc, u32x4 v) {
#pragma unroll
    for (int d = 0; d < 4; d++) {
        f32x2 t;
        t[0] = __uint_as_float(v[d] << 16);
        t[1] = __uint_as_float(v[d] & 0xffff0000u);
        acc[d] += t;                       // v_pk_add_f32
    }
}

__global__ __launch_bounds__(256) void agg_k(
    const unsigned short* __restrict__ G,
    const int* __restrict__ rp, const int* __restrict__ col,
    const float* __restrict__ dinv, const float* __restrict__ bias,
    float* __restrict__ Out, unsigned short* __restrict__ H,
    int colbase, int N) {
    int gid = (blockIdx.x * blockDim.x + threadIdx.x) >> 6;
    if (gid >= N) return;
    int lane = threadIdx.x & 63;
    int g = lane >> 4, i = lane & 15;

    f32x2 acc[4];
#pragma unroll
    for (int j = 0; j < 4; j++) acc[j] = (f32x2){0.f, 0.f};

    int e0 = rp[gid], e1 = rp[gid + 1];
    // virtual slot list: index e0-1 == self, then col[e0..e1).
    // group g owns slots e0-1+g, +4, +8, ... ; window of 4 in flight.
    int my = e0 - 1 + g;
    int c0 = (my < e1) ? ((my >= e0) ? __builtin_nontemporal_load(col + my) : gid)
                       : -1; my += 4;
    int c1 = (my < e1) ? __builtin_nontemporal_load(col + my) : -1; my += 4;
    int c2 = (my < e1) ? __builtin_nontemporal_load(col + my) : -1; my += 4;
    int c3 = (my < e1) ? __builtin_nontemporal_load(col + my) : -1; my += 4;

    const unsigned short* Gi = G + (size_t)i * 8;

    while (c0 >= 0) {
        int n0 = (my < e1) ? __builtin_nontemporal_load(col + my) : -1; my += 4;
        int n1 = (my < e1) ? __builtin_nontemporal_load(col + my) : -1; my += 4;
        int n2 = (my < e1) ? __builtin_nontemporal_load(col + my) : -1; my += 4;
        int n3 = (my < e1) ? __builtin_nontemporal_load(col + my) : -1; my += 4;
        int a1 = (c1 >= 0) ? c1 : gid;
        int a2 = (c2 >= 0) ? c2 : gid;
        int a3 = (c3 >= 0) ? c3 : gid;
        u32x4 v0 = *(const u32x4*)(Gi + (size_t)c0 * 128);
        u32x4 v1 = *(const u32x4*)(Gi + (size_t)a1 * 128);
        u32x4 v2 = *(const u32x4*)(Gi + (size_t)a2 * 128);
        u32x4 v3 = *(const u32x4*)(Gi + (size_t)a3 * 128);
        accum8(acc, v0);
        if (c1 >= 0) accum8(acc, v1);
        if (c2 >= 0) accum8(acc, v2);
        if (c3 >= 0) accum8(acc, v3);
        c0 = n0; c1 = n1; c2 = n2; c3 = n3;
    }

    float a8[8];
#pragma unroll
    for (int d = 0; d < 4; d++) { a8[2 * d] = acc[d][0]; a8[2 * d + 1] = acc[d][1]; }
#pragma unroll
    for (int j = 0; j < 8; j++) a8[j] += __shfl_xor(a8[j], 16, 64);
#pragma unroll
    for (int j = 0; j < 8; j++) a8[j] += __shfl_xor(a8[j], 32, 64);

    if (g == 0) {
        float di = dinv[gid];
        const f32x4* bp = (const f32x4*)(bias + i * 8);
        f32x4 b0 = bp[0], b1 = bp[1];
        f32x4 o0, o1;
#pragma unroll
        for (int j = 0; j < 4; j++) {
            o0[j] = fmaxf(a8[j] * di + b0[j], 0.f);
            o1[j] = fmaxf(a8[j + 4] * di + b1[j], 0.f);
        }
        float* orow = Out + (size_t)gid * 256 + colbase + i * 8;
        __builtin_nontemporal_store(o0, (f32x4*)orow);
        __builtin_nontemporal_store(o1, (f32x4*)(orow + 4));
        if (H) {
            bf16x8 hv;
#pragma unroll
            for (int j = 0; j < 4; j++) {
                hv[j]     = (short)f2bf(o0[j]);
                hv[j + 4] = (short)f2bf(o1[j]);
            }
            __builtin_nontemporal_store(hv, (bf16x8*)(H + (size_t)gid * 128 + i * 8));
        }
    }
}

extern "C" void kernel_launch(void* const* d_in, const int* in_sizes, int n_in,
                              void* d_out, int out_size, void* d_ws, size_t ws_size,
                              hipStream_t stream) {
    const float* x  = (const float*)d_in[0];   // [N,128] f32
    const float* W1 = (const float*)d_in[1];   // [128,128] f32
    const float* b1 = (const float*)d_in[2];   // [128] f32
    const float* W2 = (const float*)d_in[3];
    const float* b2 = (const float*)d_in[4];
    const int* ei = (const int*)d_in[5];       // [2,E] int32

    const int N = in_sizes[0] / 128;
    const int E = in_sizes[5] / 2;
    const int* src = ei;
    const int* dst = ei + E;
    const int NBK = (N + 511) >> 9;            // 196 for N=100000 (<= MAXNBK)

    char* ws = (char*)d_ws;
    int*      gCnt = (int*)(ws + OFF_GCNT);
    int*      rp   = (int*)(ws + OFF_RP);
    float*    dinv = (float*)(ws + OFF_DINV);
    unsigned short* WT1 = (unsigned short*)(ws + OFF_WT1);
    unsigned short* WT2 = (unsigned short*)(ws + OFF_WT2);
    int*      col  = (int*)(ws + OFF_COL);
    unsigned* gBuf = (unsigned*)(ws + OFF_G);          // dead after build_k
    unsigned short* G = (unsigned short*)(ws + OFF_G); // overlays gBuf
    unsigned short* H1 = (ws_size >= (size_t)WS_NEED)
                         ? (unsigned short*)(ws + OFF_H1) : nullptr;
    float* out = (float*)d_out;

    // 7 dispatches (was 9): prep folds memset + both W transposes.
    prep_k<<<64, 256, 0, stream>>>(W1, W2, WT1, WT2, gCnt, NBK);
    bin_k<<<(E + 4095) / 4096, 256, 0, stream>>>(src, dst, gCnt, gBuf, E, NBK);
    build_k<<<NBK, 256, 0, stream>>>(gBuf, gCnt, rp, dinv, col, NBK, N);

    int gb = (N + 63) / 64;
    int ab = (N + 3) / 4;

    // Layer 1 (A = x, f32)
    gemm_scale<1><<<gb, 256, 0, stream>>>(x, 128, WT1, dinv, G, N);
    agg_k<<<ab, 256, 0, stream>>>(G, rp, col, dinv, b1, out, H1, 0, N);
    // Layer 2 (A = h1: bf16 H1 if scratch allows, else f32 rows of out)
    if (H1) {
        gemm_scale<0><<<gb, 256, 0, stream>>>(H1, 128, WT2, dinv, G, N);
    } else {
        gemm_scale<1><<<gb, 256, 0, stream>>>(out, 256, WT2, dinv, G, N);
    }
    agg_k<<<ab, 256, 0, stream>>>(G, rp, col, dinv, b2, out, nullptr, 128, N);
}